// Round 8
// baseline (4037.377 us; speedup 1.0000x reference)
//
#include <hip/hip_runtime.h>

#define B_   64
#define C_   256
#define D_   128
#define HW_  1024
#define K_   1024
#define N_   65536
#define MARGIN 1e-5f

// numpy pairwise-sum emulation for n=128 contiguous f32 — SCALAR 8-accumulator
// path: r[j]=a[j]; for i=8..120 step 8: r[j]+=a[i+j];
// res = ((r0+r1)+(r2+r3)) + ((r4+r5)+(r6+r7)).   (verified: R4-R7 passed)
template <typename F>
__device__ __forceinline__ float np_sum128(F ld) {
#pragma clang fp contract(off)
    float r0 = ld(0), r1 = ld(1), r2 = ld(2), r3 = ld(3);
    float r4 = ld(4), r5 = ld(5), r6 = ld(6), r7 = ld(7);
#pragma unroll
    for (int i = 8; i < 128; i += 8) {
        r0 = r0 + ld(i + 0); r1 = r1 + ld(i + 1);
        r2 = r2 + ld(i + 2); r3 = r3 + ld(i + 3);
        r4 = r4 + ld(i + 4); r5 = r5 + ld(i + 5);
        r6 = r6 + ld(i + 6); r7 = r7 + ld(i + 7);
    }
    return ((r0 + r1) + (r2 + r3)) + ((r4 + r5) + (r6 + r7));
}

// ---------------- K0: enorm[k] = np.sum(embed[k]*embed[k]) emulated ----------------
__global__ __launch_bounds__(256) void k0_norms(const float* __restrict__ embed,
                                                float* __restrict__ enorm) {
#pragma clang fp contract(off)
    int k = blockIdx.x * 256 + threadIdx.x;
    if (k >= K_) return;
    const float* e = embed + (size_t)k * D_;
    enorm[k] = np_sum128([&](int i) { float v = e[i]; return v * v; });
}

// ---------------- K1: zf[n][d] = einsum-f32 emulation (sequential c, mul+add, no FMA) ----------------
__global__ __launch_bounds__(256) void k1_proj(const float* __restrict__ z,
                                               const float* __restrict__ w,
                                               const float* __restrict__ bias,
                                               float* __restrict__ zp) {
#pragma clang fp contract(off)
    __shared__ float zs[64][64];    // [cc][hw_l]
    __shared__ float wsh[64][128];  // [cc][d]
    const int b   = blockIdx.x >> 4;
    const int hw0 = (blockIdx.x & 15) << 6;
    const int t   = threadIdx.x;
    const int hwg = (t & 7) * 8;
    const int dg  = (t >> 3) * 4;

    float acc[8][4];
#pragma unroll
    for (int i = 0; i < 8; ++i)
#pragma unroll
        for (int j = 0; j < 4; ++j) acc[i][j] = 0.f;

    for (int ct = 0; ct < C_; ct += 64) {
        __syncthreads();
#pragma unroll
        for (int i = 0; i < 16; ++i) {
            int idx = i * 256 + t;
            int cc = idx >> 6, hwl = idx & 63;
            zs[cc][hwl] = z[(((size_t)b * C_ + ct + cc) << 10) + hw0 + hwl];
        }
#pragma unroll
        for (int i = 0; i < 32; ++i) {
            int idx = i * 256 + t;
            int cc = idx >> 7, d = idx & 127;
            wsh[cc][d] = w[(size_t)d * C_ + ct + cc];
        }
        __syncthreads();
#pragma unroll 2
        for (int cc = 0; cc < 64; ++cc) {       // c strictly ascending across ct blocks
            float4 za = *(const float4*)&zs[cc][hwg];
            float4 zb = *(const float4*)&zs[cc][hwg + 4];
            float4 wv = *(const float4*)&wsh[cc][dg];
            float zv[8]  = {za.x, za.y, za.z, za.w, zb.x, zb.y, zb.z, zb.w};
            float wva[4] = {wv.x, wv.y, wv.z, wv.w};
#pragma unroll
            for (int i = 0; i < 8; ++i)
#pragma unroll
                for (int j = 0; j < 4; ++j) {
                    float p = zv[i] * wva[j];    // round mul
                    acc[i][j] = acc[i][j] + p;   // round add (no contraction)
                }
        }
    }
#pragma unroll
    for (int i = 0; i < 8; ++i)
#pragma unroll
        for (int j = 0; j < 4; ++j) {
            float v = acc[i][j] + bias[dg + j];
            zp[(((size_t)b * HW_ + hw0 + hwg + i) << 7) + dg + j] = v;
        }
}

// ---------------- K2: argmin_k of np-f32 B = fl32(fl32(Z - 2*zdot) + E) ----------------
// 4-way d-split: each lane holds zr[32] (fits the allocator's 128-VGPR target,
// killing the R6/R7 scratch spill). 4-lane groups share one row; full dot via
// 2x shfl_xor butterfly (bitwise-identical across the group). z-rows also in
// padded LDS for znorm + the rare exact-refine sequential chain.
__global__ __launch_bounds__(256) void k2_argmin(const float* __restrict__ zp,
                                                 const float* __restrict__ embed,
                                                 const float* __restrict__ enorm,
                                                 int* __restrict__ bestk_ws,
                                                 float* __restrict__ out_idx) {
#pragma clang fp contract(off)
    __shared__ float zl[64][129];                // +1 pad: conflict-light refine/znorm reads
    const int t   = threadIdx.x;
    const int n0  = blockIdx.x * 64;
    const int row = t >> 2;                      // 0..63  (16 rows per wave)
    const int q   = t & 3;                       // d-quarter 0..3

#pragma unroll
    for (int i = 0; i < 32; ++i) {               // stage 64 rows (coalesced)
        int idx = i * 256 + t;
        zl[idx >> 7][idx & 127] = zp[(size_t)n0 * 128 + idx];
    }
    __syncthreads();

    // own 32-element quarter -> registers
    float zr[32];
#pragma unroll
    for (int j = 0; j < 32; ++j) zr[j] = zl[row][q * 32 + j];

    // znorm: np.sum(zf*zf) — squares rounded, scalar-8 pairwise tree (from LDS)
    const float znorm = np_sum128([&](int i) { float v = zl[row][i]; return v * v; });

    float best32 = 1e30f;          // f32 prefilter proxy: enorm - 2 z.e
    float bestB  = 1e30f;          // np-emulated quantized dist
    int   bestk  = K_;
    unsigned long long cand64 = 0; // 6 x 10-bit packed candidates
    int   cnt = 0;

    auto refine = [&](int kk) {    // exact np-bin: ascending-d f32 FMA chain (verified R4-R7)
#pragma clang fp contract(off)
        const float* e = embed + ((size_t)kk << 7);
        float s = 0.f;
#pragma unroll
        for (int d2 = 0; d2 < 128; ++d2)
            s = fmaf(zl[row][d2], e[d2], s);
        float T  = 2.0f * s;
        float A  = znorm - T;                 // bin-maker 1 (mag ~13)
        float Bv = A + enorm[kk];             // bin-maker 2
        if (Bv < bestB || (Bv == bestB && kk < bestk)) { bestB = Bv; bestk = kk; }
    };
    auto flush = [&]() {
#pragma unroll
        for (int i = 0; i < 6; ++i)
            if (i < cnt) refine((int)((cand64 >> (10 * i)) & 1023ull));
        cand64 = 0; cnt = 0;
    };

#pragma unroll 1
    for (int k = 0; k < K_; ++k) {
        const float4* e4 = (const float4*)(embed + ((size_t)k << 7) + q * 32);
        float s0 = 0.f, s1 = 0.f, s2 = 0.f, s3 = 0.f;
#pragma unroll
        for (int j = 0; j < 8; j += 4) {
            float4 a  = e4[j + 0];
            float4 b2 = e4[j + 1];
            float4 c2 = e4[j + 2];
            float4 d2 = e4[j + 3];
            s0 = fmaf(zr[4*j +  0], a.x,  s0); s0 = fmaf(zr[4*j +  1], a.y,  s0);
            s0 = fmaf(zr[4*j +  2], a.z,  s0); s0 = fmaf(zr[4*j +  3], a.w,  s0);
            s1 = fmaf(zr[4*j +  4], b2.x, s1); s1 = fmaf(zr[4*j +  5], b2.y, s1);
            s1 = fmaf(zr[4*j +  6], b2.z, s1); s1 = fmaf(zr[4*j +  7], b2.w, s1);
            s2 = fmaf(zr[4*j +  8], c2.x, s2); s2 = fmaf(zr[4*j +  9], c2.y, s2);
            s2 = fmaf(zr[4*j + 10], c2.z, s2); s2 = fmaf(zr[4*j + 11], c2.w, s2);
            s3 = fmaf(zr[4*j + 12], d2.x, s3); s3 = fmaf(zr[4*j + 13], d2.y, s3);
            s3 = fmaf(zr[4*j + 14], d2.z, s3); s3 = fmaf(zr[4*j + 15], d2.w, s3);
        }
        float sq = (s0 + s1) + (s2 + s3);               // this lane's quarter-dot
        float sp = sq + __shfl_xor(sq, 1, 64);          // pair  (bitwise-symmetric)
        float s  = sp + __shfl_xor(sp, 2, 64);          // full dot, identical in group
        float dist = fmaf(-2.f, s, enorm[k]);
        if (dist < best32 + MARGIN) {        // np-winner provably buffered (bound ~6e-6)
            best32 = fminf(best32, dist);
            if (cnt == 6) flush();
            cand64 |= (unsigned long long)(k & 1023) << (10 * cnt);
            ++cnt;
        }
    }
    flush();

    if (q == 0) {                                       // group-identical result
        bestk_ws[n0 + row] = bestk;
        out_idx[n0 + row]  = (float)bestk;
    }
}

// ---------------- K3: gather + NCHW transpose ----------------
__global__ __launch_bounds__(256) void k3_gather(const float* __restrict__ embed,
                                                 const int* __restrict__ bestk,
                                                 float* __restrict__ out0) {
    __shared__ float tile[64][129];
    const int b   = blockIdx.x >> 4;
    const int hw0 = (blockIdx.x & 15) << 6;
    const int t   = threadIdx.x;
    const int n0  = b * HW_ + hw0;
#pragma unroll
    for (int i = 0; i < 32; ++i) {
        int idx = i * 256 + t;
        int hwl = idx >> 7, d = idx & 127;
        int k = bestk[n0 + hwl];
        tile[hwl][d] = embed[(size_t)k * 128 + d];
    }
    __syncthreads();
#pragma unroll
    for (int i = 0; i < 32; ++i) {
        int idx = i * 256 + t;
        int d = idx >> 6, hwl = idx & 63;
        out0[(((size_t)b * D_ + d) << 10) + hw0 + hwl] = tile[hwl][d];
    }
}

extern "C" void kernel_launch(void* const* d_in, const int* in_sizes, int n_in,
                              void* d_out, int out_size, void* d_ws, size_t ws_size,
                              hipStream_t stream) {
    const float* z     = (const float*)d_in[0];
    const float* pw    = (const float*)d_in[1];
    const float* pb    = (const float*)d_in[2];
    const float* embed = (const float*)d_in[3];

    float* out0 = (float*)d_out;
    float* out1 = (float*)d_out + (size_t)B_ * D_ * HW_;

    const size_t zp_bytes = (size_t)N_ * D_ * 4;           // 32 MB
    float* zp    = (float*)d_ws;
    float* enorm = (float*)((char*)d_ws + zp_bytes);
    int*   bestk = (int*)  ((char*)d_ws + zp_bytes + 4096);

    hipLaunchKernelGGL(k0_norms,  dim3(4),    dim3(256), 0, stream, embed, enorm);
    hipLaunchKernelGGL(k1_proj,   dim3(1024), dim3(256), 0, stream, z, pw, pb, zp);
    hipLaunchKernelGGL(k2_argmin, dim3(1024), dim3(256), 0, stream, zp, embed, enorm, bestk, out1);
    hipLaunchKernelGGL(k3_gather, dim3(1024), dim3(256), 0, stream, embed, bestk, out0);
}

// Round 9
// 408.430 us; speedup vs baseline: 9.8851x; 9.8851x over previous
//
#include <hip/hip_runtime.h>

#define B_   64
#define C_   256
#define D_   128
#define HW_  1024
#define K_   1024
#define N_   65536
#define MARGIN_PREF 1.2e-3f

typedef __attribute__((ext_vector_type(8))) short short8;
typedef __attribute__((ext_vector_type(4))) float f32x4;

__device__ __forceinline__ unsigned short f2bf(float f) {   // RNE f32->bf16
    unsigned u = __float_as_uint(f);
    return (unsigned short)((u + 0x7FFFu + ((u >> 16) & 1u)) >> 16);
}
__device__ __forceinline__ unsigned long long packdk(float d, int k) {  // order-preserving
    unsigned u = __float_as_uint(d);
    u = (u & 0x80000000u) ? ~u : (u | 0x80000000u);
    return ((unsigned long long)u << 10) | (unsigned)k;
}
__device__ __forceinline__ float unpackd(unsigned long long key) {
    unsigned u = (unsigned)(key >> 10);
    u = (u & 0x80000000u) ? (u ^ 0x80000000u) : ~u;
    return __uint_as_float(u);
}
__device__ __forceinline__ unsigned long long min64(unsigned long long a, unsigned long long b) {
    return a < b ? a : b;
}

// numpy pairwise-sum emulation, n=128 — scalar 8-accumulator tree (verified R4-R8)
template <typename F>
__device__ __forceinline__ float np_sum128(F ld) {
#pragma clang fp contract(off)
    float r0 = ld(0), r1 = ld(1), r2 = ld(2), r3 = ld(3);
    float r4 = ld(4), r5 = ld(5), r6 = ld(6), r7 = ld(7);
#pragma unroll
    for (int i = 8; i < 128; i += 8) {
        r0 = r0 + ld(i + 0); r1 = r1 + ld(i + 1);
        r2 = r2 + ld(i + 2); r3 = r3 + ld(i + 3);
        r4 = r4 + ld(i + 4); r5 = r5 + ld(i + 5);
        r6 = r6 + ld(i + 6); r7 = r7 + ld(i + 7);
    }
    return ((r0 + r1) + (r2 + r3)) + ((r4 + r5) + (r6 + r7));
}

// ---------------- K0: enorm (np bins) + embed -> bf16 ----------------
__global__ __launch_bounds__(256) void k0_norms(const float* __restrict__ embed,
                                                float* __restrict__ enorm,
                                                unsigned short* __restrict__ ebf) {
#pragma clang fp contract(off)
    int k = blockIdx.x * 256 + threadIdx.x;
    if (k >= K_) return;
    const float* e = embed + (size_t)k * D_;
    enorm[k] = np_sum128([&](int i) { float v = e[i]; return v * v; });
#pragma unroll 8
    for (int i = 0; i < 128; ++i) ebf[(size_t)k * 128 + i] = f2bf(e[i]);
}

// ---------------- K1: einsum-f32 emulation (sequential c, mul+add, no FMA) + bf16 copy ----------------
__global__ __launch_bounds__(256) void k1_proj(const float* __restrict__ z,
                                               const float* __restrict__ w,
                                               const float* __restrict__ bias,
                                               float* __restrict__ zp,
                                               unsigned short* __restrict__ zbf) {
#pragma clang fp contract(off)
    __shared__ float zs[64][64];
    __shared__ float wsh[64][128];
    const int b   = blockIdx.x >> 4;
    const int hw0 = (blockIdx.x & 15) << 6;
    const int t   = threadIdx.x;
    const int hwg = (t & 7) * 8;
    const int dg  = (t >> 3) * 4;

    float acc[8][4];
#pragma unroll
    for (int i = 0; i < 8; ++i)
#pragma unroll
        for (int j = 0; j < 4; ++j) acc[i][j] = 0.f;

    for (int ct = 0; ct < C_; ct += 64) {
        __syncthreads();
#pragma unroll
        for (int i = 0; i < 16; ++i) {
            int idx = i * 256 + t;
            int cc = idx >> 6, hwl = idx & 63;
            zs[cc][hwl] = z[(((size_t)b * C_ + ct + cc) << 10) + hw0 + hwl];
        }
#pragma unroll
        for (int i = 0; i < 32; ++i) {
            int idx = i * 256 + t;
            int cc = idx >> 7, d = idx & 127;
            wsh[cc][d] = w[(size_t)d * C_ + ct + cc];
        }
        __syncthreads();
#pragma unroll 2
        for (int cc = 0; cc < 64; ++cc) {
            float4 za = *(const float4*)&zs[cc][hwg];
            float4 zb = *(const float4*)&zs[cc][hwg + 4];
            float4 wv = *(const float4*)&wsh[cc][dg];
            float zv[8]  = {za.x, za.y, za.z, za.w, zb.x, zb.y, zb.z, zb.w};
            float wva[4] = {wv.x, wv.y, wv.z, wv.w};
#pragma unroll
            for (int i = 0; i < 8; ++i)
#pragma unroll
                for (int j = 0; j < 4; ++j) {
                    float p = zv[i] * wva[j];
                    acc[i][j] = acc[i][j] + p;
                }
        }
    }
#pragma unroll
    for (int i = 0; i < 8; ++i)
#pragma unroll
        for (int j = 0; j < 4; ++j) {
            float v = acc[i][j] + bias[dg + j];
            size_t off = (((size_t)b * HW_ + hw0 + hwg + i) << 7) + dg + j;
            zp[off]  = v;
            zbf[off] = f2bf(v);
        }
}

// ---------------- K0z: znorm[n] = np.sum(zf*zf) per row (np bins) ----------------
__global__ __launch_bounds__(256) void k0z_znorm(const float* __restrict__ zp,
                                                 float* __restrict__ znorm) {
#pragma clang fp contract(off)
    __shared__ float zl[64][129];          // +1 pad: conflict-free column reads
    const int t = threadIdx.x, n0 = blockIdx.x * 64;
#pragma unroll
    for (int i = 0; i < 32; ++i) {
        int idx = i * 256 + t;
        zl[idx >> 7][idx & 127] = zp[(size_t)n0 * 128 + idx];
    }
    __syncthreads();
    if (t < 64)
        znorm[n0 + t] = np_sum128([&](int i) { float v = zl[t][i]; return v * v; });
}

// ---------------- K2: MFMA prefilter + margin-buffered exact np-bin rescue ----------------
// grid 512 x 256 threads. Wave owns 32 rows (2 row-tiles); block stages one
// 16x128 bf16 e-tile per k-tile in padded LDS (row stride 272B).
__global__ __launch_bounds__(256) void k2_argmin(const unsigned short* __restrict__ zbf,
                                                 const unsigned short* __restrict__ ebf,
                                                 const float* __restrict__ zp,
                                                 const float* __restrict__ embed,
                                                 const float* __restrict__ enorm,
                                                 const float* __restrict__ znorm,
                                                 int* __restrict__ bestk_ws,
                                                 float* __restrict__ out_idx) {
    __shared__ unsigned char etile[16 * 272];
    const int t   = threadIdx.x;
    const int l   = t & 63;
    const int wid = t >> 6;
    const int r0  = blockIdx.x * 128 + wid * 32;
    const int lr  = l & 15;          // A: e-row(k-in-tile) / B: z-col(row) / C: col(row)
    const int lh  = l >> 4;          // frag sub-index

    // z fragments (B operand), held in regs: 2 row-tiles x 4 d-tiles, 16B/lane each
    short8 zfrag[2][4];
#pragma unroll
    for (int rt = 0; rt < 2; ++rt)
#pragma unroll
        for (int dt = 0; dt < 4; ++dt)
            zfrag[rt][dt] = *(const short8*)(zbf + (((size_t)(r0 + rt * 16 + lr)) << 7) + dt * 32 + lh * 8);

    const int srow = t >> 4, scol = t & 15;                 // staging: 16B/thread

    // ---- Phase A: running min of packed (dist,k) ----
    unsigned long long bk0 = ~0ull, bk1 = ~0ull;
#pragma unroll 1
    for (int kt = 0; kt < 64; ++kt) {
        __syncthreads();
        *(short8*)(etile + srow * 272 + scol * 16) =
            *(const short8*)(ebf + (((size_t)(kt * 16 + srow)) << 7) + scol * 8);
        __syncthreads();
        short8 af[4];
#pragma unroll
        for (int dt = 0; dt < 4; ++dt)
            af[dt] = *(const short8*)(etile + lr * 272 + dt * 64 + lh * 16);
        f32x4 en4 = *(const f32x4*)(enorm + kt * 16 + lh * 4);
#pragma unroll
        for (int rt = 0; rt < 2; ++rt) {
            f32x4 acc = {0.f, 0.f, 0.f, 0.f};
#pragma unroll
            for (int dt = 0; dt < 4; ++dt)
                acc = __builtin_amdgcn_mfma_f32_16x16x32_bf16(af[dt], zfrag[rt][dt], acc, 0, 0, 0);
#pragma unroll
            for (int reg = 0; reg < 4; ++reg) {
                float dist = fmaf(-2.f, acc[reg], en4[reg]);
                int kk = kt * 16 + lh * 4 + reg;
                unsigned long long key = packdk(dist, kk);
                if (rt == 0) bk0 = min64(bk0, key); else bk1 = min64(bk1, key);
            }
        }
    }
    {   // cross-lane row-min (lanes l, l^16, l^32 share a row)
        unsigned long long o;
        o = __shfl_xor(bk0, 16, 64); bk0 = min64(bk0, o);
        o = __shfl_xor(bk0, 32, 64); bk0 = min64(bk0, o);
        o = __shfl_xor(bk1, 16, 64); bk1 = min64(bk1, o);
        o = __shfl_xor(bk1, 32, 64); bk1 = min64(bk1, o);
    }
    const float thr0 = unpackd(bk0) + MARGIN_PREF;
    const float thr1 = unpackd(bk1) + MARGIN_PREF;

    // ---- Phase B: bitwise-identical recompute, collect candidates ----
    unsigned long long ca0 = 0, cb0 = 0, ca1 = 0, cb1 = 0;
    int cnt0 = 0, cnt1 = 0;
#pragma unroll 1
    for (int kt = 0; kt < 64; ++kt) {
        __syncthreads();
        *(short8*)(etile + srow * 272 + scol * 16) =
            *(const short8*)(ebf + (((size_t)(kt * 16 + srow)) << 7) + scol * 8);
        __syncthreads();
        short8 af[4];
#pragma unroll
        for (int dt = 0; dt < 4; ++dt)
            af[dt] = *(const short8*)(etile + lr * 272 + dt * 64 + lh * 16);
        f32x4 en4 = *(const f32x4*)(enorm + kt * 16 + lh * 4);
#pragma unroll
        for (int rt = 0; rt < 2; ++rt) {
            f32x4 acc = {0.f, 0.f, 0.f, 0.f};
#pragma unroll
            for (int dt = 0; dt < 4; ++dt)
                acc = __builtin_amdgcn_mfma_f32_16x16x32_bf16(af[dt], zfrag[rt][dt], acc, 0, 0, 0);
#pragma unroll
            for (int reg = 0; reg < 4; ++reg) {
                float dist = fmaf(-2.f, acc[reg], en4[reg]);
                int kk = kt * 16 + lh * 4 + reg;
                if (rt == 0) {
                    if (dist < thr0) {
                        if (cnt0 < 6)       ca0 |= (unsigned long long)kk << (10 * cnt0);
                        else if (cnt0 < 12) cb0 |= (unsigned long long)kk << (10 * (cnt0 - 6));
                        ++cnt0;
                    }
                } else {
                    if (dist < thr1) {
                        if (cnt1 < 6)       ca1 |= (unsigned long long)kk << (10 * cnt1);
                        else if (cnt1 < 12) cb1 |= (unsigned long long)kk << (10 * (cnt1 - 6));
                        ++cnt1;
                    }
                }
            }
        }
    }

    // ---- Phase C: exact np-bin refine of candidates (R4-verified chain) ----
    unsigned long long fin[2];
#pragma unroll
    for (int rt = 0; rt < 2; ++rt) {
        const int myrow = r0 + rt * 16 + lr;
        const float* zrow = zp + (size_t)myrow * 128;
        const float  zn   = znorm[myrow];
        unsigned long long best = ~0ull;
        unsigned long long ca = rt == 0 ? ca0 : ca1, cb = rt == 0 ? cb0 : cb1;
        int cnt = rt == 0 ? cnt0 : cnt1;

        auto refine = [&](int kk) {
#pragma clang fp contract(off)
            const float* e = embed + ((size_t)kk << 7);
            float s = 0.f;
#pragma unroll 1
            for (int d = 0; d < 128; ++d) s = fmaf(zrow[d], e[d], s);
            float T  = 2.0f * s;
            float A  = zn - T;
            float Bv = A + enorm[kk];
            best = min64(best, packdk(Bv, kk));
        };

        if (cnt <= 12) {
#pragma unroll
            for (int i = 0; i < 6; ++i)
                if (i < cnt) refine((int)((ca >> (10 * i)) & 1023ull));
#pragma unroll
            for (int i = 6; i < 12; ++i)
                if (i < cnt) refine((int)((cb >> (10 * (i - 6))) & 1023ull));
        } else {             // overflow fallback (P ~ 1e-10): refine lane's whole subset
#pragma unroll 1
            for (int kt = 0; kt < 64; ++kt)
#pragma unroll
                for (int reg = 0; reg < 4; ++reg) refine(kt * 16 + lh * 4 + reg);
        }
        unsigned long long o;
        o = __shfl_xor(best, 16, 64); best = min64(best, o);
        o = __shfl_xor(best, 32, 64); best = min64(best, o);
        fin[rt] = best;
    }

    if (l < 16) {
#pragma unroll
        for (int rt = 0; rt < 2; ++rt) {
            int row = r0 + rt * 16 + l;
            int kk  = (int)(fin[rt] & 1023ull);
            bestk_ws[row] = kk;
            out_idx[row]  = (float)kk;
        }
    }
}

// ---------------- K3: gather + NCHW transpose ----------------
__global__ __launch_bounds__(256) void k3_gather(const float* __restrict__ embed,
                                                 const int* __restrict__ bestk,
                                                 float* __restrict__ out0) {
    __shared__ float tile[64][129];
    const int b   = blockIdx.x >> 4;
    const int hw0 = (blockIdx.x & 15) << 6;
    const int t   = threadIdx.x;
    const int n0  = b * HW_ + hw0;
#pragma unroll
    for (int i = 0; i < 32; ++i) {
        int idx = i * 256 + t;
        int hwl = idx >> 7, d = idx & 127;
        int k = bestk[n0 + hwl];
        tile[hwl][d] = embed[(size_t)k * 128 + d];
    }
    __syncthreads();
#pragma unroll
    for (int i = 0; i < 32; ++i) {
        int idx = i * 256 + t;
        int d = idx >> 6, hwl = idx & 63;
        out0[(((size_t)b * D_ + d) << 10) + hw0 + hwl] = tile[hwl][d];
    }
}

extern "C" void kernel_launch(void* const* d_in, const int* in_sizes, int n_in,
                              void* d_out, int out_size, void* d_ws, size_t ws_size,
                              hipStream_t stream) {
    const float* z     = (const float*)d_in[0];
    const float* pw    = (const float*)d_in[1];
    const float* pb    = (const float*)d_in[2];
    const float* embed = (const float*)d_in[3];

    float* out0 = (float*)d_out;
    float* out1 = (float*)d_out + (size_t)B_ * D_ * HW_;

    char* ws = (char*)d_ws;
    float*          zp    = (float*)ws;                                   // 32 MB
    unsigned short* zbf   = (unsigned short*)(ws + (32u << 20));          // 16 MB
    unsigned short* ebf   = (unsigned short*)(ws + (48u << 20));          // 256 KB
    float*          enorm = (float*)(ws + (48u << 20) + (256u << 10));    // 4 KB
    float*          znorm = (float*)(ws + (49u << 20));                   // 256 KB
    int*            bestk = (int*)  (ws + (50u << 20));                   // 256 KB

    hipLaunchKernelGGL(k0_norms,  dim3(4),    dim3(256), 0, stream, embed, enorm, ebf);
    hipLaunchKernelGGL(k1_proj,   dim3(1024), dim3(256), 0, stream, z, pw, pb, zp, zbf);
    hipLaunchKernelGGL(k0z_znorm, dim3(1024), dim3(256), 0, stream, zp, znorm);
    hipLaunchKernelGGL(k2_argmin, dim3(512),  dim3(256), 0, stream,
                       zbf, ebf, zp, embed, enorm, znorm, bestk, out1);
    hipLaunchKernelGGL(k3_gather, dim3(1024), dim3(256), 0, stream, embed, bestk, out0);
}